// Round 2
// baseline (9500.040 us; speedup 1.0000x reference)
//
#include <hip/hip_runtime.h>
#include <hip/hip_bf16.h>

// Problem sizes (fixed by reference): L=2, B=128, T=512, D=64, F=512
#define FDIM   512
#define BATCH  128
#define TSTEPS 512
#define GDIM   2048   // 4*FDIM gate columns

typedef __attribute__((ext_vector_type(8))) short bf16x8;   // 8 bf16 = 4 VGPRs (MFMA A/B frag)
typedef __attribute__((ext_vector_type(4))) float f32x4;    // MFMA C/D frag

__device__ __forceinline__ ushort f32_to_bf16(float v) {
    union { float f; unsigned u; } c; c.f = v;
    unsigned b = c.u;
    unsigned r = (b + 0x7FFFu + ((b >> 16) & 1u)) >> 16;   // RNE
    return (ushort)r;
}

__device__ __forceinline__ float sigmoidf_(float x) {
    return 1.0f / (1.0f + expf(-x));
}

// ---------------------------------------------------------------------------
// One-time: fp32 -> bf16 weight conversion + bias combine (b_ih + b_hh)
// ---------------------------------------------------------------------------
__global__ __launch_bounds__(256) void convert_weights(
    const float* __restrict__ Wih0, const float* __restrict__ Whh0,
    const float* __restrict__ Wih1, const float* __restrict__ Whh1,
    const float* __restrict__ bih0, const float* __restrict__ bhh0,
    const float* __restrict__ bih1, const float* __restrict__ bhh1,
    ushort* __restrict__ w0, ushort* __restrict__ w1,
    ushort* __restrict__ w2, ushort* __restrict__ w3,
    float* __restrict__ bc0, float* __restrict__ bc1)
{
    int idx = blockIdx.x * 256 + threadIdx.x;      // grid covers 2048*512
    if (idx < GDIM * FDIM) {
        w0[idx] = f32_to_bf16(Wih0[idx]);
        w1[idx] = f32_to_bf16(Whh0[idx]);
        w2[idx] = f32_to_bf16(Wih1[idx]);
        w3[idx] = f32_to_bf16(Whh1[idx]);
    }
    if (idx < GDIM) {
        bc0[idx] = bih0[idx] + bhh0[idx];
        bc1[idx] = bih1[idx] + bhh1[idx];
    }
}

// ---------------------------------------------------------------------------
// One-time: h0 = c0 = x @ W_init.T + b_init  (per layer); lf = bf16(last_feat)
// hbuf layout: [layer][parity][B*F] bf16; init writes parity=1 (prev of t=0)
// ---------------------------------------------------------------------------
__global__ __launch_bounds__(256) void init_state(
    const float* __restrict__ x,      // (2,128,64)
    const float* __restrict__ Winit,  // (512,64)
    const float* __restrict__ binit,  // (512,)
    const float* __restrict__ lastf,  // (128,512)
    ushort* __restrict__ hbuf,        // [2][2][B*F]
    float*  __restrict__ cbuf,        // [2][B*F]
    ushort* __restrict__ lf)          // [B*F]
{
    int idx = blockIdx.x * 256 + threadIdx.x;      // 0 .. 131071 (2*128*512)
    int f   = idx & (FDIM - 1);
    int row = idx >> 9;                            // layer*128 + b, 0..255
    const float* xr = x + row * 64;
    const float* wr = Winit + f * 64;
    float s = binit[f];
    #pragma unroll
    for (int k = 0; k < 64; ++k) s += xr[k] * wr[k];
    int layer = row >> 7;
    int b     = row & 127;
    cbuf[layer * (BATCH * FDIM) + b * FDIM + f] = s;
    hbuf[(layer * 2 + 1) * (BATCH * FDIM) + b * FDIM + f] = f32_to_bf16(s);
    if (idx < BATCH * FDIM) lf[idx] = f32_to_bf16(lastf[idx]);
}

// ---------------------------------------------------------------------------
// One LSTM cell phase: gates = inp@Wih.T + h@Whh.T + bc ; c,h update.
// Grid: 256 WGs of 256 threads. WG tile: 16 batch rows x 16 features x 4 gates.
//   blockIdx: mt = bid&7 (batch tile), ft = bid>>3 (feature tile)
//   wave w = gate g (torch order i,f,g,o). MFMA 16x16x32 bf16, K=512+512.
// Epilogue (gates via LDS): fp32 sigmoid/tanh, c in-place fp32, h out bf16,
// optional fp32 out row (layer 1 -> d_out).
// ---------------------------------------------------------------------------
__global__ __launch_bounds__(256) void lstm_cell(
    const ushort* __restrict__ inp,   // (B,F) bf16
    const ushort* __restrict__ hst,   // (B,F) bf16 (prev hidden)
    float*        __restrict__ cst,   // (B,F) fp32 (in-place)
    const ushort* __restrict__ Wih,   // (2048,512) bf16 row-major
    const ushort* __restrict__ Whh,   // (2048,512) bf16 row-major
    const float*  __restrict__ bc,    // (2048,) combined bias
    ushort*       __restrict__ hout,  // (B,F) bf16
    float*        __restrict__ outp)  // nullptr or (B,F) fp32 slice of d_out
{
    const int lane = threadIdx.x & 63;
    const int g    = threadIdx.x >> 6;        // gate 0..3
    const int mt   = blockIdx.x & 7;          // 8 * 16 = 128 batch
    const int ft   = blockIdx.x >> 3;         // 32 * 16 = 512 features

    const int mrow = mt * 16 + (lane & 15);               // batch row (A frag)
    const int wrow = g * FDIM + ft * 16 + (lane & 15);    // weight row (B frag)
    const int koff = (lane >> 4) * 8;                     // k sub-offset

    f32x4 acc = {0.f, 0.f, 0.f, 0.f};

    const ushort* arow = inp + mrow * FDIM;
    const ushort* wr   = Wih + (size_t)wrow * FDIM;
    #pragma unroll
    for (int ks = 0; ks < 16; ++ks) {
        int k = ks * 32 + koff;
        bf16x8 a = *reinterpret_cast<const bf16x8*>(arow + k);
        bf16x8 b = *reinterpret_cast<const bf16x8*>(wr + k);
        acc = __builtin_amdgcn_mfma_f32_16x16x32_bf16(a, b, acc, 0, 0, 0);
    }
    arow = hst + mrow * FDIM;
    wr   = Whh + (size_t)wrow * FDIM;
    #pragma unroll
    for (int ks = 0; ks < 16; ++ks) {
        int k = ks * 32 + koff;
        bf16x8 a = *reinterpret_cast<const bf16x8*>(arow + k);
        bf16x8 b = *reinterpret_cast<const bf16x8*>(wr + k);
        acc = __builtin_amdgcn_mfma_f32_16x16x32_bf16(a, b, acc, 0, 0, 0);
    }

    // Stage gates (with bias) into LDS.  C/D map: col=lane&15, row=(lane>>4)*4+j
    __shared__ float gbuf[4][16][16];
    {
        const int col   = lane & 15;
        const int rbase = (lane >> 4) * 4;
        const float bias = bc[wrow];
        #pragma unroll
        for (int j = 0; j < 4; ++j)
            gbuf[g][rbase + j][col] = acc[j] + bias;
    }
    __syncthreads();

    // 256 threads -> 16x16 (b,f) elementwise LSTM update
    {
        const int tid = threadIdx.x;
        const int r = tid >> 4, c = tid & 15;
        const int b = mt * 16 + r;
        const int f = ft * 16 + c;
        const int idx = b * FDIM + f;
        float gi = gbuf[0][r][c];
        float gf = gbuf[1][r][c];
        float gg = gbuf[2][r][c];
        float go = gbuf[3][r][c];
        float ig = sigmoidf_(gi);
        float fg = sigmoidf_(gf);
        float cd = tanhf(gg);
        float og = sigmoidf_(go);
        float cn = fg * cst[idx] + ig * cd;
        float hn = og * tanhf(cn);
        cst[idx]  = cn;
        hout[idx] = f32_to_bf16(hn);
        if (outp) outp[idx] = hn;
    }
}

// ---------------------------------------------------------------------------
extern "C" void kernel_launch(void* const* d_in, const int* in_sizes, int n_in,
                              void* d_out, int out_size, void* d_ws, size_t ws_size,
                              hipStream_t stream)
{
    const float* x      = (const float*)d_in[0];
    const float* lastf  = (const float*)d_in[1];
    const float* W_init = (const float*)d_in[2];
    const float* b_init = (const float*)d_in[3];
    const float* W_ih0  = (const float*)d_in[4];
    const float* W_hh0  = (const float*)d_in[5];
    const float* b_ih0  = (const float*)d_in[6];
    const float* b_hh0  = (const float*)d_in[7];
    const float* W_ih1  = (const float*)d_in[8];
    const float* W_hh1  = (const float*)d_in[9];
    const float* b_ih1  = (const float*)d_in[10];
    const float* b_hh1  = (const float*)d_in[11];
    // d_in[12]/d_in[13] = W_out / b_out: dead code in the reference.
    float* out = (float*)d_out;

    char* ws = (char*)d_ws;
    size_t off = 0;
    const size_t WSZ = (size_t)GDIM * FDIM;        // 1,048,576 elems per matrix
    ushort* wih0 = (ushort*)(ws + off); off += WSZ * 2;
    ushort* whh0 = (ushort*)(ws + off); off += WSZ * 2;
    ushort* wih1 = (ushort*)(ws + off); off += WSZ * 2;
    ushort* whh1 = (ushort*)(ws + off); off += WSZ * 2;
    ushort* hbuf = (ushort*)(ws + off); off += (size_t)2 * 2 * BATCH * FDIM * 2;
    ushort* lf   = (ushort*)(ws + off); off += (size_t)BATCH * FDIM * 2;
    float*  cbuf = (float*)(ws + off);  off += (size_t)2 * BATCH * FDIM * 4;
    float*  bc0  = (float*)(ws + off);  off += GDIM * 4;
    float*  bc1  = (float*)(ws + off);  off += GDIM * 4;

    convert_weights<<<(GDIM * FDIM + 255) / 256, 256, 0, stream>>>(
        W_ih0, W_hh0, W_ih1, W_hh1, b_ih0, b_hh0, b_ih1, b_hh1,
        wih0, whh0, wih1, whh1, bc0, bc1);

    init_state<<<(2 * BATCH * FDIM + 255) / 256, 256, 0, stream>>>(
        x, W_init, b_init, lastf, hbuf, cbuf, lf);

    auto hb = [&](int layer, int par) {
        return hbuf + (size_t)(layer * 2 + par) * (BATCH * FDIM);
    };
    float* c0 = cbuf;
    float* c1 = cbuf + (size_t)BATCH * FDIM;

    for (int t = 0; t < TSTEPS; ++t) {
        const int p = t & 1, q = p ^ 1;
        const ushort* in0 = (t == 0) ? lf : hb(1, q);
        lstm_cell<<<256, 256, 0, stream>>>(in0, hb(0, q), c0,
                                           wih0, whh0, bc0, hb(0, p), nullptr);
        lstm_cell<<<256, 256, 0, stream>>>(hb(0, p), hb(1, q), c1,
                                           wih1, whh1, bc1, hb(1, p),
                                           out + (size_t)t * (BATCH * FDIM));
    }
}